// Round 7
// baseline (210.225 us; speedup 1.0000x reference)
//
#include <hip/hip_runtime.h>

#define WI 512
#define HI 512
#define WO 2048
#define HO 2048
#define NIMG 8
#define CCH 3
#define EPS 1e-8f
#define PLANE (HI * WI)

#define TPB   512     // 8 waves per WG, one output row per WG
#define NWAVE 8
#define WPX   256     // px per wave window
#define PXT   4       // consecutive px per thread
#define CAPW  520     // texel slots per wave-private LDS slot

// ===========================================================================
// v15: v14 (wave-autonomous pipelines, ~37us, first structure to break the
// 44us floor) + intra-wave software pipelining of the layer loop:
//   prefetch(layer i+1 globals -> regs) BEFORE blend(layer i)
// so the ~300-900cy global-load latency of the next layer hides under the
// current layer's blend VALU/LDS work. No barriers, no LDS double-buffer:
// same-wave DS ops execute in order (commit(i+1) writes are issued after
// blend(i) reads), so a single wave-private slot is hazard-free. Scalar
// layer state is double-buffered in registers (cur/nxt).
//  - __launch_bounds__(512,6): VGPR cap 85 protects the LDS-set occupancy
//    (49.9KB -> 3 blocks/CU = 24 waves/CU); prefetch buffer is +24 VGPR.
//  - sweep1 (R>256, w<512 minority) stays synchronous inside commit.
//  - sampling math expression-identical to v11/v13/v14's verified paths;
//    wave-granular occlusion cull unchanged.
// ===========================================================================
__launch_bounds__(TPB, 6)
__global__ void diffcomp_v15(const float* __restrict__ src,
                             const float* __restrict__ bg,
                             const float* __restrict__ coor,
                             float* __restrict__ out) {
    __shared__ __align__(16) float cs[NWAVE][CAPW * CCH];   // 49,920 B
    __shared__ float4 stA[NIMG];   // (A2, D, my, wy0)
    __shared__ float4 stY[NIMG];   // (wy1, y0o_f, y1o_f, 0)

    const int tid = threadIdx.x;
    const int b0  = blockIdx.x;
    const int row = ((b0 & 7) << 8) | (b0 >> 3);   // bijective XCD swizzle
    const float HW1 = 0.5f * (float)(WI - 1);      // 255.5

    if (tid < NIMG) {
        const float cx  = coor[tid * 4 + 0];
        const float cy  = coor[tid * 4 + 1];
        const float cw  = coor[tid * 4 + 2];
        const float chh = coor[tid * 4 + 3];
        const float xx = (1.0f / (1.0f + expf(-cx))) * (float)WO;
        const float yy = (1.0f / (1.0f + expf(-cy))) * (float)HO;
        const float w  = (1.0f / (1.0f + expf(-cw))) * (float)WO;
        const float h  = (1.0f / (1.0f + expf(-chh))) * (float)HO;
        const float a  = (float)WO / (w + EPS);
        const float bb = (float)HO / (h + EPS);
        const float ty = (2.0f / (float)HO) * ((float)HO * 0.5f - yy) * bb;

        // y chain (reference form, verified r2-r6)
        const float ys  = (2.0f * (float)row + 1.0f) / (float)HO - 1.0f;
        const float gy  = bb * ys + ty;
        const float iy  = ((gy + 1.0f) * (float)HI - 1.0f) * 0.5f;
        const float y0f = floorf(iy);
        const float fy1 = iy - y0f;
        const float fy0 = 1.0f - fy1;
        const float y1f = y0f + 1.0f;
        const float v0  = (y0f >= 0.0f && y0f < (float)HI) ? 1.0f : 0.0f;
        const float v1  = (y1f >= 0.0f && y1f < (float)HI) ? 1.0f : 0.0f;
        const float wy0 = fy0 * v0;
        const float wy1 = fy1 * v1;
        const float my  = wy0 + wy1;
        const float y0of = fminf(fmaxf(y0f, 0.0f), (float)(HI - 1)) * (float)WI;
        const float y1of = fminf(fmaxf(y1f, 0.0f), (float)(HI - 1)) * (float)WI;

        // x mapping: ix(wo) = A2*(wo + D) + HW1
        const float A2 = a * ((float)WI / (float)WO);
        const float D  = 0.5f - xx;

        stA[tid] = make_float4(A2, D, my, wy0);
        stY[tid] = make_float4(wy1, y0of, y1of, 0.0f);
    }
    __syncthreads();          // the ONLY barrier

    const int wid  = tid >> 6;
    const int lane = tid & 63;
    const int pw0  = wid << 8;                 // wave's first px of the row
    const int px0  = pw0 + (lane << 2);
    const int gbase = row * WO + px0;

    // ---- wave-granular visibility / interior / occlusion (wave-uniform) ----
    unsigned wvis = 0u, wintr = 0u;
    int jw = -1;
#pragma unroll
    for (int n = 0; n < NIMG; n++) {
        const float4 SA = stA[n];
        if (SA.z > 0.0f) {
            const float ixF = fmaf(SA.x, (float)pw0 + SA.y, HW1);
            const float ixL = fmaf(SA.x, (float)(pw0 + WPX - 1) + SA.y, HW1);
            if (!(ixL <= -1.0f || ixF >= (float)WI)) {
                wvis |= (1u << n);
                if (ixF >= 0.0f && ixL < (float)(WI - 1)) {
                    wintr |= (1u << n);
                    if (SA.z == 1.0f) jw = n;   // my==1 exact => m==1 on wave
                }
            }
        }
    }
    if (jw >= 0) wvis &= ~((1u << jw) - 1u);    // layers below jw are hidden

    float acc[CCH][PXT];
    if (jw < 0) {
#pragma unroll
        for (int c = 0; c < CCH; c++) {
            const float4 bv = *(const float4*)&bg[c * (HO * WO) + gbase];
            acc[c][0] = bv.x; acc[c][1] = bv.y; acc[c][2] = bv.z; acc[c][3] = bv.w;
        }
    } else {
#pragma unroll
        for (int c = 0; c < CCH; c++)
#pragma unroll
            for (int p = 0; p < PXT; p++)
                acc[c][p] = 0.0f;
    }

    float xpf[PXT];
#pragma unroll
    for (int p = 0; p < PXT; p++) xpf[p] = (float)(px0 + p);

    float* const slot = cs[wid];               // wave-private texel slot

    // ---- layer list (back-to-front) ----
    int lay[NIMG]; int nl = 0;
    {
        unsigned t = wvis;
        while (t) { lay[nl++] = (int)__builtin_ctz(t); t &= t - 1u; }
    }

    if (nl) {
        struct LS {                            // wave-uniform layer scalars
            float A2, D, my, wy0, wy1;
            int   t0a, R, lim, y0o, y1o;
        };
        LS cur, nxt;
        float4 PF0[CCH], PF1[CCH];             // prefetch buffer (sweep0)

        auto prefetch = [&](int n, LS& L, float4* r0, float4* r1) {
            const float4 SA = stA[n];
            const float4 SY = stY[n];
            L.A2 = SA.x; L.D = SA.y; L.my = SA.z; L.wy0 = SA.w; L.wy1 = SY.x;
            L.y0o = (int)SY.y; L.y1o = (int)SY.z;
            const float ixF = fmaf(L.A2, (float)pw0 + L.D, HW1);
            const float ixL = fmaf(L.A2, (float)(pw0 + WPX - 1) + L.D, HW1);
            const int t0 = (int)fminf(fmaxf(floorf(ixF), 0.0f), (float)(WI - 1));
            const int t1 = (int)fminf(fmaxf(floorf(ixL) + 1.0f, 0.0f), (float)(WI - 1));
            L.t0a = t0 & ~3;
            int R = (t1 - L.t0a + 4) & ~3;
            if (R > WI - L.t0a) R = WI - L.t0a;
            L.R = R; L.lim = t1 - L.t0a;
            const int xo = lane << 2;
            if (xo < L.R) {
                const float* ib = src + n * (CCH * PLANE) + L.t0a + xo;
#pragma unroll
                for (int c = 0; c < CCH; c++) {
                    r0[c] = *(const float4*)(ib + c * PLANE + L.y0o);
                    r1[c] = *(const float4*)(ib + c * PLANE + L.y1o);
                }
            }
        };

        prefetch(lay[0], nxt, PF0, PF1);

        for (int i = 0; i < nl; i++) {
            const int n = lay[i];
            cur = nxt;

            // ---- commit: y-lerp prefetched sweep0 into the wave slot ----
            {
                const int xo = lane << 2;
                if (xo < cur.R) {
                    float wv[12];
#pragma unroll
                    for (int t = 0; t < 4; t++)
#pragma unroll
                        for (int c = 0; c < CCH; c++)
                            wv[t * CCH + c] = ((const float*)&PF0[c])[t] * cur.wy0
                                            + ((const float*)&PF1[c])[t] * cur.wy1;
                    float* dst = &slot[xo * CCH];
                    ((float4*)dst)[0] = make_float4(wv[0], wv[1], wv[2],  wv[3]);
                    ((float4*)dst)[1] = make_float4(wv[4], wv[5], wv[6],  wv[7]);
                    ((float4*)dst)[2] = make_float4(wv[8], wv[9], wv[10], wv[11]);
                }
                // sweep1 (R>256: w<512 minority) -- synchronous
                if (cur.R > 256) {
                    const int xo1 = (lane << 2) + 256;
                    if (xo1 < cur.R) {
                        const float* ib = src + n * (CCH * PLANE) + cur.t0a + xo1;
                        float4 r0[CCH], r1[CCH];
#pragma unroll
                        for (int c = 0; c < CCH; c++) {
                            r0[c] = *(const float4*)(ib + c * PLANE + cur.y0o);
                            r1[c] = *(const float4*)(ib + c * PLANE + cur.y1o);
                        }
                        float wv[12];
#pragma unroll
                        for (int t = 0; t < 4; t++)
#pragma unroll
                            for (int c = 0; c < CCH; c++)
                                wv[t * CCH + c] = ((const float*)&r0[c])[t] * cur.wy0
                                                + ((const float*)&r1[c])[t] * cur.wy1;
                        float* dst = &slot[xo1 * CCH];
                        ((float4*)dst)[0] = make_float4(wv[0], wv[1], wv[2],  wv[3]);
                        ((float4*)dst)[1] = make_float4(wv[4], wv[5], wv[6],  wv[7]);
                        ((float4*)dst)[2] = make_float4(wv[8], wv[9], wv[10], wv[11]);
                    }
                }
            }

            // ---- issue next layer's global loads; they fly during blend ----
            if (i + 1 < nl) prefetch(lay[i + 1], nxt, PF0, PF1);

            // ---- blend current layer from the wave slot ----
            const float A2 = cur.A2, Dv = cur.D, my = cur.my;
            const float t0af = (float)cur.t0a;
            if ((wintr >> n) & 1u) {
                // interior: k,k+1 in [0,lim] for every px (monotone fma proof)
                const float omy = 1.0f - my;
                if (omy == 0.0f) {                  // my==1: pure replace
#pragma unroll
                    for (int p = 0; p < PXT; p++) {
                        const float ix  = fmaf(A2, xpf[p] + Dv, HW1);
                        const float x0f = floorf(ix);
                        const float fx1 = ix - x0f;
                        const int   k   = (int)(x0f - t0af);
                        const float* tp = slot + k * CCH;
#pragma unroll
                        for (int c = 0; c < CCH; c++) {
                            const float q0 = tp[c];
                            const float q1 = tp[c + CCH];
                            acc[c][p] = q0 + fx1 * (q1 - q0);
                        }
                    }
                } else {                            // y-edge row: uniform m=my
#pragma unroll
                    for (int p = 0; p < PXT; p++) {
                        const float ix  = fmaf(A2, xpf[p] + Dv, HW1);
                        const float x0f = floorf(ix);
                        const float fx1 = ix - x0f;
                        const int   k   = (int)(x0f - t0af);
                        const float* tp = slot + k * CCH;
#pragma unroll
                        for (int c = 0; c < CCH; c++) {
                            const float q0 = tp[c];
                            const float q1 = tp[c + CCH];
                            const float sc = q0 + fx1 * (q1 - q0);
                            acc[c][p] = acc[c][p] * omy + my * sc;
                        }
                    }
                }
            } else {
                // boundary wave: full reference math with clamps (verified)
#pragma unroll
                for (int p = 0; p < PXT; p++) {
                    const float ix  = fmaf(A2, xpf[p] + Dv, HW1);
                    const float x0f = floorf(ix);
                    const float fx1 = ix - x0f;
                    const float fx0 = 1.0f - fx1;
                    const float x1f = x0f + 1.0f;
                    const float v0  = (x0f >= 0.0f && x0f < (float)WI) ? 1.0f : 0.0f;
                    const float v1  = (x1f >= 0.0f && x1f < (float)WI) ? 1.0f : 0.0f;
                    const float wx0 = fx0 * v0;
                    const float wx1 = fx1 * v1;
                    int x0r = (int)fminf(fmaxf(x0f, 0.0f), (float)(WI - 1)) - cur.t0a;
                    int x1r = (int)fminf(fmaxf(x1f, 0.0f), (float)(WI - 1)) - cur.t0a;
                    x0r = min(max(x0r, 0), cur.lim);
                    x1r = min(max(x1r, 0), cur.lim);
                    const float m  = my * (wx0 + wx1);
                    const float om = 1.0f - m;
#pragma unroll
                    for (int c = 0; c < CCH; c++) {
                        const float q0 = slot[x0r * CCH + c];
                        const float q1 = slot[x1r * CCH + c];
                        acc[c][p] = acc[c][p] * om + (q0 * wx0 + q1 * wx1) * m;
                    }
                }
            }
        }
    }

#pragma unroll
    for (int c = 0; c < CCH; c++)
        *(float4*)&out[c * (HO * WO) + gbase] =
            make_float4(acc[c][0], acc[c][1], acc[c][2], acc[c][3]);
}

extern "C" void kernel_launch(void* const* d_in, const int* in_sizes, int n_in,
                              void* d_out, int out_size, void* d_ws, size_t ws_size,
                              hipStream_t stream) {
    const float* src  = (const float*)d_in[0];   // [8,3,512,512]
    const float* bg   = (const float*)d_in[1];   // [1,3,2048,2048]
    const float* coor = (const float*)d_in[2];   // [8,4]
    float* out = (float*)d_out;                  // [1,3,2048,2048]
    (void)d_ws; (void)ws_size;

    hipLaunchKernelGGL(diffcomp_v15, dim3(HO), dim3(TPB), 0, stream,
                       src, bg, coor, out);
}

// Round 8
// 172.603 us; speedup vs baseline: 1.2180x; 1.2180x over previous
//
#include <hip/hip_runtime.h>

#define WI 512
#define HI 512
#define WO 2048
#define HO 2048
#define NIMG 8
#define CCH 3
#define EPS 1e-8f
#define PLANE (HI * WI)

#define TPB   512     // 8 waves per WG, one output row per WG
#define NWAVE 8
#define WPX   256     // px per wave window
#define PXT   4       // consecutive px per thread
#define CAPW  520     // texel slots per wave-private LDS slot

// uniform-value helpers: force provably wave-uniform scalars into SGPRs
__device__ __forceinline__ float rflf(float x) {
    return __uint_as_float(__builtin_amdgcn_readfirstlane(__float_as_uint(x)));
}
__device__ __forceinline__ int rfli(int x) {
    return __builtin_amdgcn_readfirstlane(x);
}

// ===========================================================================
// v16: round-6's intra-wave layer-prefetch theory, re-implemented register-
// safe. v15's regression was NOT the theory: runtime-indexed lay[] put
// per-thread state in scratch (WRITE_SIZE 49->220MB). v16:
//  - layer walk by bitmask ctz only (no arrays, rule #20 clean)
//  - ONE prefetch buffer P0/P1 (compile-time indices only): commit consumes
//    it before the next issue overwrites it -> no double buffer, no copies
//  - all wave-uniform layer scalars through readfirstlane -> SGPRs
//    (frees ~20 VGPRs; keeps allocator under the 85-VGPR / 6-wave line
//    that the 50KB LDS (3 blocks/CU = 24 waves) demands)
//  - otherwise byte-identical to v14 (~37us control): wave-autonomous,
//    zero barriers after setup, wave-granular occlusion cull, verified math
// ===========================================================================
__launch_bounds__(TPB, 6)
__global__ void diffcomp_v16(const float* __restrict__ src,
                             const float* __restrict__ bg,
                             const float* __restrict__ coor,
                             float* __restrict__ out) {
    __shared__ __align__(16) float cs[NWAVE][CAPW * CCH];   // 49,920 B
    __shared__ float4 stA[NIMG];   // (A2, D, my, wy0)
    __shared__ float4 stY[NIMG];   // (wy1, y0o_f, y1o_f, 0)

    const int tid = threadIdx.x;
    const int b0  = blockIdx.x;
    const int row = ((b0 & 7) << 8) | (b0 >> 3);   // bijective XCD swizzle
    const float HW1 = 0.5f * (float)(WI - 1);      // 255.5

    if (tid < NIMG) {
        const float cx  = coor[tid * 4 + 0];
        const float cy  = coor[tid * 4 + 1];
        const float cw  = coor[tid * 4 + 2];
        const float chh = coor[tid * 4 + 3];
        const float xx = (1.0f / (1.0f + expf(-cx))) * (float)WO;
        const float yy = (1.0f / (1.0f + expf(-cy))) * (float)HO;
        const float w  = (1.0f / (1.0f + expf(-cw))) * (float)WO;
        const float h  = (1.0f / (1.0f + expf(-chh))) * (float)HO;
        const float a  = (float)WO / (w + EPS);
        const float bb = (float)HO / (h + EPS);
        const float ty = (2.0f / (float)HO) * ((float)HO * 0.5f - yy) * bb;

        // y chain (reference form, verified r2-r6)
        const float ys  = (2.0f * (float)row + 1.0f) / (float)HO - 1.0f;
        const float gy  = bb * ys + ty;
        const float iy  = ((gy + 1.0f) * (float)HI - 1.0f) * 0.5f;
        const float y0f = floorf(iy);
        const float fy1 = iy - y0f;
        const float fy0 = 1.0f - fy1;
        const float y1f = y0f + 1.0f;
        const float v0  = (y0f >= 0.0f && y0f < (float)HI) ? 1.0f : 0.0f;
        const float v1  = (y1f >= 0.0f && y1f < (float)HI) ? 1.0f : 0.0f;
        const float wy0 = fy0 * v0;
        const float wy1 = fy1 * v1;
        const float my  = wy0 + wy1;
        const float y0of = fminf(fmaxf(y0f, 0.0f), (float)(HI - 1)) * (float)WI;
        const float y1of = fminf(fmaxf(y1f, 0.0f), (float)(HI - 1)) * (float)WI;

        // x mapping: ix(wo) = A2*(wo + D) + HW1
        const float A2 = a * ((float)WI / (float)WO);
        const float D  = 0.5f - xx;

        stA[tid] = make_float4(A2, D, my, wy0);
        stY[tid] = make_float4(wy1, y0of, y1of, 0.0f);
    }
    __syncthreads();          // the ONLY barrier

    const int wid  = tid >> 6;
    const int lane = tid & 63;
    const int pw0  = wid << 8;                 // wave's first px of the row
    const int px0  = pw0 + (lane << 2);
    const int gbase = row * WO + px0;

    // ---- wave-granular visibility / interior / occlusion (wave-uniform) ----
    unsigned wvis = 0u, wintr = 0u;
    int jw = -1;
#pragma unroll
    for (int n = 0; n < NIMG; n++) {
        const float4 SA = stA[n];
        if (SA.z > 0.0f) {
            const float ixF = fmaf(SA.x, (float)pw0 + SA.y, HW1);
            const float ixL = fmaf(SA.x, (float)(pw0 + WPX - 1) + SA.y, HW1);
            if (!(ixL <= -1.0f || ixF >= (float)WI)) {
                wvis |= (1u << n);
                if (ixF >= 0.0f && ixL < (float)(WI - 1)) {
                    wintr |= (1u << n);
                    if (SA.z == 1.0f) jw = n;   // my==1 exact => m==1 on wave
                }
            }
        }
    }
    if (jw >= 0) wvis &= ~((1u << jw) - 1u);    // layers below jw are hidden

    float acc[CCH][PXT];
    if (jw < 0) {
#pragma unroll
        for (int c = 0; c < CCH; c++) {
            const float4 bv = *(const float4*)&bg[c * (HO * WO) + gbase];
            acc[c][0] = bv.x; acc[c][1] = bv.y; acc[c][2] = bv.z; acc[c][3] = bv.w;
        }
    } else {
#pragma unroll
        for (int c = 0; c < CCH; c++)
#pragma unroll
            for (int p = 0; p < PXT; p++)
                acc[c][p] = 0.0f;
    }

    float xpf[PXT];
#pragma unroll
    for (int p = 0; p < PXT; p++) xpf[p] = (float)(px0 + p);

    float* const slot = cs[wid];               // wave-private texel slot

    if (wvis) {
        // ---- current/next layer state: named SGPR-resident scalars ----
        float cA2, cD, cmy, cwy0, cwy1;  int ct0a, cR, clim, cy0o, cy1o;
        float nA2, nD, nmy, nwy0, nwy1;  int nt0a, nR, nlim, ny0o, ny1o;
        float4 P0[CCH], P1[CCH];         // single prefetch buffer (sweep0)

        // compute uniform state for layer n (into the n* slots)
        auto ldstate = [&](int n) {
            const float4 SA = stA[n];
            const float4 SY = stY[n];
            nA2 = rflf(SA.x); nD = rflf(SA.y); nmy = rflf(SA.z);
            nwy0 = rflf(SA.w); nwy1 = rflf(SY.x);
            ny0o = rfli((int)SY.y); ny1o = rfli((int)SY.z);
            const float ixF = fmaf(nA2, (float)pw0 + nD, HW1);
            const float ixL = fmaf(nA2, (float)(pw0 + WPX - 1) + nD, HW1);
            const int t0 = (int)fminf(fmaxf(floorf(ixF), 0.0f), (float)(WI - 1));
            const int t1 = (int)fminf(fmaxf(floorf(ixL) + 1.0f, 0.0f), (float)(WI - 1));
            int t0a = t0 & ~3;
            int R = (t1 - t0a + 4) & ~3;
            if (R > WI - t0a) R = WI - t0a;
            nt0a = rfli(t0a); nR = rfli(R); nlim = rfli(t1 - t0a);
        };
        // issue layer-n sweep0 global loads into P0/P1 (uses n* state)
        auto issue = [&](int n) {
            const int xo = lane << 2;
            if (xo < nR) {
                const float* ib = src + n * (CCH * PLANE) + nt0a + xo;
#pragma unroll
                for (int c = 0; c < CCH; c++) {
                    P0[c] = *(const float4*)(ib + c * PLANE + ny0o);
                    P1[c] = *(const float4*)(ib + c * PLANE + ny1o);
                }
            }
        };
        auto adv = [&]() {                     // n* -> c* (scalar copies only)
            cA2 = nA2; cD = nD; cmy = nmy; cwy0 = nwy0; cwy1 = nwy1;
            ct0a = nt0a; cR = nR; clim = nlim; cy0o = ny0o; cy1o = ny1o;
        };

        int n = (int)__builtin_ctz(wvis);
        unsigned rest = wvis & (wvis - 1u);
        ldstate(n); issue(n); adv();

        while (true) {
            const int nn = rest ? (int)__builtin_ctz(rest) : -1;

            // ---- commit sweep0: y-lerp prefetched regs into the wave slot ----
            {
                const int xo = lane << 2;
                if (xo < cR) {
                    float wv[12];
#pragma unroll
                    for (int t = 0; t < 4; t++)
#pragma unroll
                        for (int c = 0; c < CCH; c++)
                            wv[t * CCH + c] = ((const float*)&P0[c])[t] * cwy0
                                            + ((const float*)&P1[c])[t] * cwy1;
                    float* dst = &slot[xo * CCH];
                    ((float4*)dst)[0] = make_float4(wv[0], wv[1], wv[2],  wv[3]);
                    ((float4*)dst)[1] = make_float4(wv[4], wv[5], wv[6],  wv[7]);
                    ((float4*)dst)[2] = make_float4(wv[8], wv[9], wv[10], wv[11]);
                }
                // sweep1 (R>256: w<512 minority) -- synchronous
                if (cR > 256) {
                    const int xo1 = (lane << 2) + 256;
                    if (xo1 < cR) {
                        const float* ib = src + n * (CCH * PLANE) + ct0a + xo1;
                        float4 r0[CCH], r1[CCH];
#pragma unroll
                        for (int c = 0; c < CCH; c++) {
                            r0[c] = *(const float4*)(ib + c * PLANE + cy0o);
                            r1[c] = *(const float4*)(ib + c * PLANE + cy1o);
                        }
                        float wv[12];
#pragma unroll
                        for (int t = 0; t < 4; t++)
#pragma unroll
                            for (int c = 0; c < CCH; c++)
                                wv[t * CCH + c] = ((const float*)&r0[c])[t] * cwy0
                                                + ((const float*)&r1[c])[t] * cwy1;
                        float* dst = &slot[xo1 * CCH];
                        ((float4*)dst)[0] = make_float4(wv[0], wv[1], wv[2],  wv[3]);
                        ((float4*)dst)[1] = make_float4(wv[4], wv[5], wv[6],  wv[7]);
                        ((float4*)dst)[2] = make_float4(wv[8], wv[9], wv[10], wv[11]);
                    }
                }
            }

            // ---- issue next layer's loads NOW; they fly during blend ----
            if (nn >= 0) { ldstate(nn); issue(nn); }

            // ---- blend current layer from the wave slot ----
            const float t0af = (float)ct0a;
            if ((wintr >> n) & 1u) {
                // interior: k,k+1 in [0,lim] for every px (monotone fma proof)
                const float omy = 1.0f - cmy;
                if (omy == 0.0f) {                  // my==1: pure replace
#pragma unroll
                    for (int p = 0; p < PXT; p++) {
                        const float ix  = fmaf(cA2, xpf[p] + cD, HW1);
                        const float x0f = floorf(ix);
                        const float fx1 = ix - x0f;
                        const int   k   = (int)(x0f - t0af);
                        const float* tp = slot + k * CCH;
#pragma unroll
                        for (int c = 0; c < CCH; c++) {
                            const float q0 = tp[c];
                            const float q1 = tp[c + CCH];
                            acc[c][p] = q0 + fx1 * (q1 - q0);
                        }
                    }
                } else {                            // y-edge row: uniform m=my
#pragma unroll
                    for (int p = 0; p < PXT; p++) {
                        const float ix  = fmaf(cA2, xpf[p] + cD, HW1);
                        const float x0f = floorf(ix);
                        const float fx1 = ix - x0f;
                        const int   k   = (int)(x0f - t0af);
                        const float* tp = slot + k * CCH;
#pragma unroll
                        for (int c = 0; c < CCH; c++) {
                            const float q0 = tp[c];
                            const float q1 = tp[c + CCH];
                            const float sc = q0 + fx1 * (q1 - q0);
                            acc[c][p] = acc[c][p] * omy + cmy * sc;
                        }
                    }
                }
            } else {
                // boundary wave: full reference math with clamps (verified)
#pragma unroll
                for (int p = 0; p < PXT; p++) {
                    const float ix  = fmaf(cA2, xpf[p] + cD, HW1);
                    const float x0f = floorf(ix);
                    const float fx1 = ix - x0f;
                    const float fx0 = 1.0f - fx1;
                    const float x1f = x0f + 1.0f;
                    const float v0  = (x0f >= 0.0f && x0f < (float)WI) ? 1.0f : 0.0f;
                    const float v1  = (x1f >= 0.0f && x1f < (float)WI) ? 1.0f : 0.0f;
                    const float wx0 = fx0 * v0;
                    const float wx1 = fx1 * v1;
                    int x0r = (int)fminf(fmaxf(x0f, 0.0f), (float)(WI - 1)) - ct0a;
                    int x1r = (int)fminf(fmaxf(x1f, 0.0f), (float)(WI - 1)) - ct0a;
                    x0r = min(max(x0r, 0), clim);
                    x1r = min(max(x1r, 0), clim);
                    const float m  = cmy * (wx0 + wx1);
                    const float om = 1.0f - m;
#pragma unroll
                    for (int c = 0; c < CCH; c++) {
                        const float q0 = slot[x0r * CCH + c];
                        const float q1 = slot[x1r * CCH + c];
                        acc[c][p] = acc[c][p] * om + (q0 * wx0 + q1 * wx1) * m;
                    }
                }
            }

            if (nn < 0) break;
            n = nn;
            rest &= rest - 1u;
            adv();
        }
    }

#pragma unroll
    for (int c = 0; c < CCH; c++)
        *(float4*)&out[c * (HO * WO) + gbase] =
            make_float4(acc[c][0], acc[c][1], acc[c][2], acc[c][3]);
}

extern "C" void kernel_launch(void* const* d_in, const int* in_sizes, int n_in,
                              void* d_out, int out_size, void* d_ws, size_t ws_size,
                              hipStream_t stream) {
    const float* src  = (const float*)d_in[0];   // [8,3,512,512]
    const float* bg   = (const float*)d_in[1];   // [1,3,2048,2048]
    const float* coor = (const float*)d_in[2];   // [8,4]
    float* out = (float*)d_out;                  // [1,3,2048,2048]
    (void)d_ws; (void)ws_size;

    hipLaunchKernelGGL(diffcomp_v16, dim3(HO), dim3(TPB), 0, stream,
                       src, bg, coor, out);
}

// Round 9
// 132.649 us; speedup vs baseline: 1.5848x; 1.3012x over previous
//
#include <hip/hip_runtime.h>

#define WI 512
#define HI 512
#define WO 2048
#define HO 2048
#define NIMG 8
#define CCH 3
#define EPS 1e-8f
#define PLANE (HI * WI)

#define TPB   512     // 8 waves per WG, one output row per WG
#define NWAVE 8
#define WPX   256     // px per wave window
#define PXT   4       // consecutive px per thread
#define CAPW  520     // texel slots per wave-private LDS slot

// ===========================================================================
// v17: third implementation of the intra-wave layer-prefetch experiment.
// v15 spilled (runtime-indexed array), v16 still spilled (float4 arrays
// living across the while-backedge, conditionally written, address-cast).
// v17 removes the entire spill surface:
//  - prefetch buffer = six NAMED float4s (P00..P12), member access only
//  - layer state via macros writing named scalars (no lambdas/structs)
//  - plain __launch_bounds__(TPB) (v14's config; no ,6 cap -- v16's cap
//    pushed the allocator into a spill-everything solution)
// Otherwise byte-identical to v14 (~37us control): wave-autonomous waves,
// zero barriers after setup, wave-granular occlusion cull, verified math.
// Pipeline per wave: commit(i) -> issue loads(i+1) -> blend(i), so layer
// i+1's ~300-900cy global latency hides under blend(i)'s VALU/LDS work.
// Same-wave DS ordering makes the single LDS slot hazard-free.
// ===========================================================================
__launch_bounds__(TPB)
__global__ void diffcomp_v17(const float* __restrict__ src,
                             const float* __restrict__ bg,
                             const float* __restrict__ coor,
                             float* __restrict__ out) {
    __shared__ __align__(16) float cs[NWAVE][CAPW * CCH];   // 49,920 B
    __shared__ float4 stA[NIMG];   // (A2, D, my, wy0)
    __shared__ float4 stY[NIMG];   // (wy1, y0o_f, y1o_f, 0)

    const int tid = threadIdx.x;
    const int b0  = blockIdx.x;
    const int row = ((b0 & 7) << 8) | (b0 >> 3);   // bijective XCD swizzle
    const float HW1 = 0.5f * (float)(WI - 1);      // 255.5

    if (tid < NIMG) {
        const float cx  = coor[tid * 4 + 0];
        const float cy  = coor[tid * 4 + 1];
        const float cw  = coor[tid * 4 + 2];
        const float chh = coor[tid * 4 + 3];
        const float xx = (1.0f / (1.0f + expf(-cx))) * (float)WO;
        const float yy = (1.0f / (1.0f + expf(-cy))) * (float)HO;
        const float w  = (1.0f / (1.0f + expf(-cw))) * (float)WO;
        const float h  = (1.0f / (1.0f + expf(-chh))) * (float)HO;
        const float a  = (float)WO / (w + EPS);
        const float bb = (float)HO / (h + EPS);
        const float ty = (2.0f / (float)HO) * ((float)HO * 0.5f - yy) * bb;

        // y chain (reference form, verified r2-r6)
        const float ys  = (2.0f * (float)row + 1.0f) / (float)HO - 1.0f;
        const float gy  = bb * ys + ty;
        const float iy  = ((gy + 1.0f) * (float)HI - 1.0f) * 0.5f;
        const float y0f = floorf(iy);
        const float fy1 = iy - y0f;
        const float fy0 = 1.0f - fy1;
        const float y1f = y0f + 1.0f;
        const float v0  = (y0f >= 0.0f && y0f < (float)HI) ? 1.0f : 0.0f;
        const float v1  = (y1f >= 0.0f && y1f < (float)HI) ? 1.0f : 0.0f;
        const float wy0 = fy0 * v0;
        const float wy1 = fy1 * v1;
        const float my  = wy0 + wy1;
        const float y0of = fminf(fmaxf(y0f, 0.0f), (float)(HI - 1)) * (float)WI;
        const float y1of = fminf(fmaxf(y1f, 0.0f), (float)(HI - 1)) * (float)WI;

        // x mapping: ix(wo) = A2*(wo + D) + HW1
        const float A2 = a * ((float)WI / (float)WO);
        const float D  = 0.5f - xx;

        stA[tid] = make_float4(A2, D, my, wy0);
        stY[tid] = make_float4(wy1, y0of, y1of, 0.0f);
    }
    __syncthreads();          // the ONLY barrier

    const int wid  = tid >> 6;
    const int lane = tid & 63;
    const int pw0  = wid << 8;                 // wave's first px of the row
    const int px0  = pw0 + (lane << 2);
    const int gbase = row * WO + px0;
    const int xo   = lane << 2;                // staging texel offset

    // ---- wave-granular visibility / interior / occlusion (wave-uniform) ----
    unsigned wvis = 0u, wintr = 0u;
    int jw = -1;
#pragma unroll
    for (int n = 0; n < NIMG; n++) {
        const float4 SA = stA[n];
        if (SA.z > 0.0f) {
            const float ixF = fmaf(SA.x, (float)pw0 + SA.y, HW1);
            const float ixL = fmaf(SA.x, (float)(pw0 + WPX - 1) + SA.y, HW1);
            if (!(ixL <= -1.0f || ixF >= (float)WI)) {
                wvis |= (1u << n);
                if (ixF >= 0.0f && ixL < (float)(WI - 1)) {
                    wintr |= (1u << n);
                    if (SA.z == 1.0f) jw = n;   // my==1 exact => m==1 on wave
                }
            }
        }
    }
    if (jw >= 0) wvis &= ~((1u << jw) - 1u);    // layers below jw are hidden

    float acc[CCH][PXT];
    if (jw < 0) {
#pragma unroll
        for (int c = 0; c < CCH; c++) {
            const float4 bv = *(const float4*)&bg[c * (HO * WO) + gbase];
            acc[c][0] = bv.x; acc[c][1] = bv.y; acc[c][2] = bv.z; acc[c][3] = bv.w;
        }
    } else {
#pragma unroll
        for (int c = 0; c < CCH; c++)
#pragma unroll
            for (int p = 0; p < PXT; p++)
                acc[c][p] = 0.0f;
    }

    float xpf[PXT];
#pragma unroll
    for (int p = 0; p < PXT; p++) xpf[p] = (float)(px0 + p);

    float* const slot = cs[wid];               // wave-private texel slot

// compute wave-uniform state of layer n_ into named scalars
#define LDSTATE(n_, A2_, D_, my_, wy0_, wy1_, t0a_, R_, lim_, y0o_, y1o_)     \
    do {                                                                      \
        const float4 SA_ = stA[n_];                                           \
        const float4 SY_ = stY[n_];                                           \
        A2_ = SA_.x; D_ = SA_.y; my_ = SA_.z; wy0_ = SA_.w; wy1_ = SY_.x;     \
        y0o_ = (int)SY_.y; y1o_ = (int)SY_.z;                                 \
        const float ixF_ = fmaf(A2_, (float)pw0 + D_, HW1);                   \
        const float ixL_ = fmaf(A2_, (float)(pw0 + WPX - 1) + D_, HW1);       \
        const int t0_ = (int)fminf(fmaxf(floorf(ixF_), 0.0f), (float)(WI-1)); \
        const int t1_ = (int)fminf(fmaxf(floorf(ixL_) + 1.0f, 0.0f),          \
                                   (float)(WI-1));                            \
        t0a_ = t0_ & ~3;                                                      \
        int R_t = (t1_ - t0a_ + 4) & ~3;                                      \
        if (R_t > WI - t0a_) R_t = WI - t0a_;                                 \
        R_ = R_t; lim_ = t1_ - t0a_;                                          \
    } while (0)

// issue layer n_'s sweep0 global loads into the named P regs
#define ISSUE(n_, t0a_, R_, y0o_, y1o_)                                       \
    do {                                                                      \
        if (xo < R_) {                                                        \
            const float* ib_ = src + (n_) * (CCH * PLANE) + (t0a_) + xo;      \
            P00 = *(const float4*)(ib_ + 0 * PLANE + (y0o_));                 \
            P01 = *(const float4*)(ib_ + 1 * PLANE + (y0o_));                 \
            P02 = *(const float4*)(ib_ + 2 * PLANE + (y0o_));                 \
            P10 = *(const float4*)(ib_ + 0 * PLANE + (y1o_));                 \
            P11 = *(const float4*)(ib_ + 1 * PLANE + (y1o_));                 \
            P12 = *(const float4*)(ib_ + 2 * PLANE + (y1o_));                 \
        }                                                                     \
    } while (0)

    if (wvis) {
        float4 P00, P01, P02, P10, P11, P12;   // named prefetch registers
        float cA2, cD, cmy, cwy0, cwy1;  int ct0a, cR, clim, cy0o, cy1o;
        float nA2, nD, nmy, nwy0, nwy1;  int nt0a, nR, nlim, ny0o, ny1o;

        int n = (int)__builtin_ctz(wvis);
        unsigned rest = wvis & (wvis - 1u);
        LDSTATE(n, cA2, cD, cmy, cwy0, cwy1, ct0a, cR, clim, cy0o, cy1o);
        ISSUE(n, ct0a, cR, cy0o, cy1o);

        while (true) {
            const int nn = rest ? (int)__builtin_ctz(rest) : -1;

            // ---- commit sweep0: y-lerp the named P regs into the slot ----
            if (xo < cR) {
                const float t0c0 = P00.x * cwy0 + P10.x * cwy1;
                const float t0c1 = P01.x * cwy0 + P11.x * cwy1;
                const float t0c2 = P02.x * cwy0 + P12.x * cwy1;
                const float t1c0 = P00.y * cwy0 + P10.y * cwy1;
                const float t1c1 = P01.y * cwy0 + P11.y * cwy1;
                const float t1c2 = P02.y * cwy0 + P12.y * cwy1;
                const float t2c0 = P00.z * cwy0 + P10.z * cwy1;
                const float t2c1 = P01.z * cwy0 + P11.z * cwy1;
                const float t2c2 = P02.z * cwy0 + P12.z * cwy1;
                const float t3c0 = P00.w * cwy0 + P10.w * cwy1;
                const float t3c1 = P01.w * cwy0 + P11.w * cwy1;
                const float t3c2 = P02.w * cwy0 + P12.w * cwy1;
                float* dst = &slot[xo * CCH];
                ((float4*)dst)[0] = make_float4(t0c0, t0c1, t0c2, t1c0);
                ((float4*)dst)[1] = make_float4(t1c1, t1c2, t2c0, t2c1);
                ((float4*)dst)[2] = make_float4(t2c2, t3c0, t3c1, t3c2);
            }
            // sweep1 (R>256: w<512 minority) -- synchronous, block-scoped regs
            if (cR > 256) {
                const int xo1 = xo + 256;
                if (xo1 < cR) {
                    const float* ib = src + n * (CCH * PLANE) + ct0a + xo1;
                    float4 r0[CCH], r1[CCH];
#pragma unroll
                    for (int c = 0; c < CCH; c++) {
                        r0[c] = *(const float4*)(ib + c * PLANE + cy0o);
                        r1[c] = *(const float4*)(ib + c * PLANE + cy1o);
                    }
                    float wv[12];
#pragma unroll
                    for (int t = 0; t < 4; t++)
#pragma unroll
                        for (int c = 0; c < CCH; c++)
                            wv[t * CCH + c] = ((const float*)&r0[c])[t] * cwy0
                                            + ((const float*)&r1[c])[t] * cwy1;
                    float* dst = &slot[xo1 * CCH];
                    ((float4*)dst)[0] = make_float4(wv[0], wv[1], wv[2],  wv[3]);
                    ((float4*)dst)[1] = make_float4(wv[4], wv[5], wv[6],  wv[7]);
                    ((float4*)dst)[2] = make_float4(wv[8], wv[9], wv[10], wv[11]);
                }
            }

            // ---- issue next layer's loads NOW; they fly during blend ----
            if (nn >= 0) {
                LDSTATE(nn, nA2, nD, nmy, nwy0, nwy1, nt0a, nR, nlim, ny0o, ny1o);
                ISSUE(nn, nt0a, nR, ny0o, ny1o);
            }

            // ---- blend current layer from the wave slot ----
            const float t0af = (float)ct0a;
            if ((wintr >> n) & 1u) {
                // interior: k,k+1 in [0,lim] for every px (monotone fma proof)
                const float omy = 1.0f - cmy;
                if (omy == 0.0f) {                  // my==1: pure replace
#pragma unroll
                    for (int p = 0; p < PXT; p++) {
                        const float ix  = fmaf(cA2, xpf[p] + cD, HW1);
                        const float x0f = floorf(ix);
                        const float fx1 = ix - x0f;
                        const int   k   = (int)(x0f - t0af);
                        const float* tp = slot + k * CCH;
#pragma unroll
                        for (int c = 0; c < CCH; c++) {
                            const float q0 = tp[c];
                            const float q1 = tp[c + CCH];
                            acc[c][p] = q0 + fx1 * (q1 - q0);
                        }
                    }
                } else {                            // y-edge row: uniform m=my
#pragma unroll
                    for (int p = 0; p < PXT; p++) {
                        const float ix  = fmaf(cA2, xpf[p] + cD, HW1);
                        const float x0f = floorf(ix);
                        const float fx1 = ix - x0f;
                        const int   k   = (int)(x0f - t0af);
                        const float* tp = slot + k * CCH;
#pragma unroll
                        for (int c = 0; c < CCH; c++) {
                            const float q0 = tp[c];
                            const float q1 = tp[c + CCH];
                            const float sc = q0 + fx1 * (q1 - q0);
                            acc[c][p] = acc[c][p] * omy + cmy * sc;
                        }
                    }
                }
            } else {
                // boundary wave: full reference math with clamps (verified)
#pragma unroll
                for (int p = 0; p < PXT; p++) {
                    const float ix  = fmaf(cA2, xpf[p] + cD, HW1);
                    const float x0f = floorf(ix);
                    const float fx1 = ix - x0f;
                    const float fx0 = 1.0f - fx1;
                    const float x1f = x0f + 1.0f;
                    const float v0  = (x0f >= 0.0f && x0f < (float)WI) ? 1.0f : 0.0f;
                    const float v1  = (x1f >= 0.0f && x1f < (float)WI) ? 1.0f : 0.0f;
                    const float wx0 = fx0 * v0;
                    const float wx1 = fx1 * v1;
                    int x0r = (int)fminf(fmaxf(x0f, 0.0f), (float)(WI - 1)) - ct0a;
                    int x1r = (int)fminf(fmaxf(x1f, 0.0f), (float)(WI - 1)) - ct0a;
                    x0r = min(max(x0r, 0), clim);
                    x1r = min(max(x1r, 0), clim);
                    const float m  = cmy * (wx0 + wx1);
                    const float om = 1.0f - m;
#pragma unroll
                    for (int c = 0; c < CCH; c++) {
                        const float q0 = slot[x0r * CCH + c];
                        const float q1 = slot[x1r * CCH + c];
                        acc[c][p] = acc[c][p] * om + (q0 * wx0 + q1 * wx1) * m;
                    }
                }
            }

            if (nn < 0) break;
            n = nn;
            rest &= rest - 1u;
            cA2 = nA2; cD = nD; cmy = nmy; cwy0 = nwy0; cwy1 = nwy1;
            ct0a = nt0a; cR = nR; clim = nlim; cy0o = ny0o; cy1o = ny1o;
        }
    }

#pragma unroll
    for (int c = 0; c < CCH; c++)
        *(float4*)&out[c * (HO * WO) + gbase] =
            make_float4(acc[c][0], acc[c][1], acc[c][2], acc[c][3]);
}

extern "C" void kernel_launch(void* const* d_in, const int* in_sizes, int n_in,
                              void* d_out, int out_size, void* d_ws, size_t ws_size,
                              hipStream_t stream) {
    const float* src  = (const float*)d_in[0];   // [8,3,512,512]
    const float* bg   = (const float*)d_in[1];   // [1,3,2048,2048]
    const float* coor = (const float*)d_in[2];   // [8,4]
    float* out = (float*)d_out;                  // [1,3,2048,2048]
    (void)d_ws; (void)ws_size;

    hipLaunchKernelGGL(diffcomp_v17, dim3(HO), dim3(TPB), 0, stream,
                       src, bg, coor, out);
}

// Round 10
// 125.250 us; speedup vs baseline: 1.6784x; 1.0591x over previous
//
#include <hip/hip_runtime.h>

#define WI 512
#define HI 512
#define WO 2048
#define HO 2048
#define NIMG 8
#define CCH 3
#define EPS 1e-8f
#define PLANE (HI * WI)

#define TPB   512     // 8 waves per WG, one output row per WG
#define NWAVE 8
#define WPX   256     // px per wave window
#define PXT   4       // consecutive px per thread
#define CAPW  520     // texel slots per wave-private LDS slot

// ===========================================================================
// v18: v14's body (measured best, spill-clean, ~36-37us) with ONE change:
// the row<->block mapping. v14's swizzle gave each XCD a contiguous 256-row
// BAND; per-row work varies strongly (layer overlap), so banding made the
// busiest XCD the critical path -- matching v17's counters (Occupancy 19.5%
// avg = idle-tail, all pipes <25%). v18 maps b0[2:0]=xcd, b0[6:3]=run,
// b0[10:7]=group: row = g*128 + xcd*16 + r. Each XCD gets 16-row contiguous
// runs strided by 128 => work balanced at 128-row granularity AND adjacent
// rows within a run keep src-row L2 locality on their XCD.
// (r9 falsified the layer-prefetch theory: clean v17 = 40.9us vs v14 ~37;
//  prefetch dropped, body reverted to v14 exactly.)
// ===========================================================================
__launch_bounds__(TPB)
__global__ void diffcomp_v18(const float* __restrict__ src,
                             const float* __restrict__ bg,
                             const float* __restrict__ coor,
                             float* __restrict__ out) {
    __shared__ __align__(16) float cs[NWAVE][CAPW * CCH];   // 49,920 B
    __shared__ float4 stA[NIMG];   // (A2, D, my, wy0)
    __shared__ float4 stY[NIMG];   // (wy1, y0o_f, y1o_f, 0)

    const int tid = threadIdx.x;
    const int b0  = blockIdx.x;
    // balanced-run mapping: xcd = b0[2:0], r = b0[6:3], g = b0[10:7]
    const int row = ((b0 >> 7) << 7) | ((b0 & 7) << 4) | ((b0 >> 3) & 15);
    const float HW1 = 0.5f * (float)(WI - 1);      // 255.5

    if (tid < NIMG) {
        const float cx  = coor[tid * 4 + 0];
        const float cy  = coor[tid * 4 + 1];
        const float cw  = coor[tid * 4 + 2];
        const float chh = coor[tid * 4 + 3];
        const float xx = (1.0f / (1.0f + expf(-cx))) * (float)WO;
        const float yy = (1.0f / (1.0f + expf(-cy))) * (float)HO;
        const float w  = (1.0f / (1.0f + expf(-cw))) * (float)WO;
        const float h  = (1.0f / (1.0f + expf(-chh))) * (float)HO;
        const float a  = (float)WO / (w + EPS);
        const float bb = (float)HO / (h + EPS);
        const float ty = (2.0f / (float)HO) * ((float)HO * 0.5f - yy) * bb;

        // y chain (reference form, verified r2-r6)
        const float ys  = (2.0f * (float)row + 1.0f) / (float)HO - 1.0f;
        const float gy  = bb * ys + ty;
        const float iy  = ((gy + 1.0f) * (float)HI - 1.0f) * 0.5f;
        const float y0f = floorf(iy);
        const float fy1 = iy - y0f;
        const float fy0 = 1.0f - fy1;
        const float y1f = y0f + 1.0f;
        const float v0  = (y0f >= 0.0f && y0f < (float)HI) ? 1.0f : 0.0f;
        const float v1  = (y1f >= 0.0f && y1f < (float)HI) ? 1.0f : 0.0f;
        const float wy0 = fy0 * v0;
        const float wy1 = fy1 * v1;
        const float my  = wy0 + wy1;
        const float y0of = fminf(fmaxf(y0f, 0.0f), (float)(HI - 1)) * (float)WI;
        const float y1of = fminf(fmaxf(y1f, 0.0f), (float)(HI - 1)) * (float)WI;

        // x mapping: ix(wo) = A2*(wo + D) + HW1
        const float A2 = a * ((float)WI / (float)WO);
        const float D  = 0.5f - xx;

        stA[tid] = make_float4(A2, D, my, wy0);
        stY[tid] = make_float4(wy1, y0of, y1of, 0.0f);
    }
    __syncthreads();          // the ONLY barrier

    const int wid  = tid >> 6;
    const int lane = tid & 63;
    const int pw0  = wid << 8;                 // wave's first px of the row
    const int px0  = pw0 + (lane << 2);
    const int gbase = row * WO + px0;

    // ---- wave-granular visibility / interior / occlusion (wave-uniform) ----
    unsigned wvis = 0u, wintr = 0u;
    int jw = -1;
#pragma unroll
    for (int n = 0; n < NIMG; n++) {
        const float4 SA = stA[n];
        if (SA.z > 0.0f) {
            const float ixF = fmaf(SA.x, (float)pw0 + SA.y, HW1);
            const float ixL = fmaf(SA.x, (float)(pw0 + WPX - 1) + SA.y, HW1);
            if (!(ixL <= -1.0f || ixF >= (float)WI)) {
                wvis |= (1u << n);
                if (ixF >= 0.0f && ixL < (float)(WI - 1)) {
                    wintr |= (1u << n);
                    if (SA.z == 1.0f) jw = n;   // my==1 exact => m==1 on wave
                }
            }
        }
    }
    if (jw >= 0) wvis &= ~((1u << jw) - 1u);    // layers below jw are hidden

    float acc[CCH][PXT];
    if (jw < 0) {
#pragma unroll
        for (int c = 0; c < CCH; c++) {
            const float4 bv = *(const float4*)&bg[c * (HO * WO) + gbase];
            acc[c][0] = bv.x; acc[c][1] = bv.y; acc[c][2] = bv.z; acc[c][3] = bv.w;
        }
    } else {
#pragma unroll
        for (int c = 0; c < CCH; c++)
#pragma unroll
            for (int p = 0; p < PXT; p++)
                acc[c][p] = 0.0f;
    }

    float xpf[PXT];
#pragma unroll
    for (int p = 0; p < PXT; p++) xpf[p] = (float)(px0 + p);

    float* const slot = cs[wid];               // wave-private texel slot

    // ---- layer loop: back-to-front, fully wave-local, no barriers ----
    unsigned rest = wvis;
    while (rest) {
        const int n = (int)__builtin_ctz(rest);
        rest &= rest - 1u;
        const float4 SA = stA[n];
        const float4 SY = stY[n];
        const float A2 = SA.x, Dv = SA.y, my = SA.z;
        const float wy0 = SA.w, wy1 = SY.x;
        const int y0o = (int)SY.y;
        const int y1o = (int)SY.z;

        // wave-window staging range (verified segment math, wave granularity)
        const float ixF = fmaf(A2, (float)pw0 + Dv, HW1);
        const float ixL = fmaf(A2, (float)(pw0 + WPX - 1) + Dv, HW1);
        const int t0  = (int)fminf(fmaxf(floorf(ixF), 0.0f), (float)(WI - 1));
        const int t1  = (int)fminf(fmaxf(floorf(ixL) + 1.0f, 0.0f), (float)(WI - 1));
        const int t0a = t0 & ~3;
        int R = (t1 - t0a + 4) & ~3;
        if (R > WI - t0a) R = WI - t0a;
        const int lim = t1 - t0a;

        const float* ib = src + n * (CCH * PLANE) + t0a;

        // stage: up to 2 sweeps x 256 texels, contiguous dwordx4, y-lerp,
        // texel-major ds_write into the wave's private slot
#pragma unroll
        for (int sw = 0; sw < 2; sw++) {
            const int xo = (lane << 2) + (sw << 8);
            if (xo < R) {
                float4 r0[CCH], r1[CCH];
#pragma unroll
                for (int c = 0; c < CCH; c++) {
                    r0[c] = *(const float4*)(ib + c * PLANE + y0o + xo);
                    r1[c] = *(const float4*)(ib + c * PLANE + y1o + xo);
                }
                float wv[12];
#pragma unroll
                for (int t = 0; t < 4; t++)
#pragma unroll
                    for (int c = 0; c < CCH; c++)
                        wv[t * CCH + c] = ((const float*)&r0[c])[t] * wy0
                                        + ((const float*)&r1[c])[t] * wy1;
                float* dst = &slot[xo * CCH];
                ((float4*)dst)[0] = make_float4(wv[0], wv[1], wv[2],  wv[3]);
                ((float4*)dst)[1] = make_float4(wv[4], wv[5], wv[6],  wv[7]);
                ((float4*)dst)[2] = make_float4(wv[8], wv[9], wv[10], wv[11]);
            }
        }
        // compiler inserts lgkmcnt before dependent ds_reads (within-wave dep)

        const float t0af = (float)t0a;
        if ((wintr >> n) & 1u) {
            // interior: k,k+1 in [0,lim] for every px (monotone fma proof)
            const float omy = 1.0f - my;
            if (omy == 0.0f) {                  // my==1: pure replace
#pragma unroll
                for (int p = 0; p < PXT; p++) {
                    const float ix  = fmaf(A2, xpf[p] + Dv, HW1);
                    const float x0f = floorf(ix);
                    const float fx1 = ix - x0f;
                    const int   k   = (int)(x0f - t0af);
                    const float* tp = slot + k * CCH;
#pragma unroll
                    for (int c = 0; c < CCH; c++) {
                        const float q0 = tp[c];
                        const float q1 = tp[c + CCH];
                        acc[c][p] = q0 + fx1 * (q1 - q0);
                    }
                }
            } else {                            // y-edge row: uniform m=my
#pragma unroll
                for (int p = 0; p < PXT; p++) {
                    const float ix  = fmaf(A2, xpf[p] + Dv, HW1);
                    const float x0f = floorf(ix);
                    const float fx1 = ix - x0f;
                    const int   k   = (int)(x0f - t0af);
                    const float* tp = slot + k * CCH;
#pragma unroll
                    for (int c = 0; c < CCH; c++) {
                        const float q0 = tp[c];
                        const float q1 = tp[c + CCH];
                        const float sc = q0 + fx1 * (q1 - q0);
                        acc[c][p] = acc[c][p] * omy + my * sc;
                    }
                }
            }
        } else {
            // boundary wave: full reference math with clamps (verified)
#pragma unroll
            for (int p = 0; p < PXT; p++) {
                const float ix  = fmaf(A2, xpf[p] + Dv, HW1);
                const float x0f = floorf(ix);
                const float fx1 = ix - x0f;
                const float fx0 = 1.0f - fx1;
                const float x1f = x0f + 1.0f;
                const float v0  = (x0f >= 0.0f && x0f < (float)WI) ? 1.0f : 0.0f;
                const float v1  = (x1f >= 0.0f && x1f < (float)WI) ? 1.0f : 0.0f;
                const float wx0 = fx0 * v0;
                const float wx1 = fx1 * v1;
                int x0r = (int)fminf(fmaxf(x0f, 0.0f), (float)(WI - 1)) - t0a;
                int x1r = (int)fminf(fmaxf(x1f, 0.0f), (float)(WI - 1)) - t0a;
                x0r = min(max(x0r, 0), lim);
                x1r = min(max(x1r, 0), lim);
                const float m  = my * (wx0 + wx1);
                const float om = 1.0f - m;
#pragma unroll
                for (int c = 0; c < CCH; c++) {
                    const float q0 = slot[x0r * CCH + c];
                    const float q1 = slot[x1r * CCH + c];
                    acc[c][p] = acc[c][p] * om + (q0 * wx0 + q1 * wx1) * m;
                }
            }
        }
    }

#pragma unroll
    for (int c = 0; c < CCH; c++)
        *(float4*)&out[c * (HO * WO) + gbase] =
            make_float4(acc[c][0], acc[c][1], acc[c][2], acc[c][3]);
}

extern "C" void kernel_launch(void* const* d_in, const int* in_sizes, int n_in,
                              void* d_out, int out_size, void* d_ws, size_t ws_size,
                              hipStream_t stream) {
    const float* src  = (const float*)d_in[0];   // [8,3,512,512]
    const float* bg   = (const float*)d_in[1];   // [1,3,2048,2048]
    const float* coor = (const float*)d_in[2];   // [8,4]
    float* out = (float*)d_out;                  // [1,3,2048,2048]
    (void)d_ws; (void)ws_size;

    hipLaunchKernelGGL(diffcomp_v18, dim3(HO), dim3(TPB), 0, stream,
                       src, bg, coor, out);
}